// Round 3
// baseline (416.360 us; speedup 1.0000x reference)
//
#include <hip/hip_runtime.h>
#include <math.h>

#define B_ 4
#define C_ 256
#define N_ 4096   // H*W
#define LDE 72    // ET row stride (ushorts): 144 B = 16-B aligned, spreads banks

typedef __attribute__((ext_vector_type(8))) short short8;
typedef __attribute__((ext_vector_type(4))) float f32x4;

__device__ inline ushort f2bf(float f) {
    uint u = __float_as_uint(f);
    return (ushort)((u + 0x7fffu + ((u >> 16) & 1u)) >> 16);   // RNE
}
__device__ inline float bflo(uint w) { return __uint_as_float(w << 16); }
__device__ inline float bfhi(uint w) { return __uint_as_float(w & 0xffff0000u); }

// ---------------------------------------------------------------------------
// P0: xbT[b][n][c] = bf16(fm+fd)  (transposed),  fdb[b][c][n] = bf16(fd)
// ---------------------------------------------------------------------------
__global__ __launch_bounds__(256) void prep_kernel(const float* __restrict__ fm,
                                                   const float* __restrict__ fd,
                                                   ushort* __restrict__ xbT,
                                                   ushort* __restrict__ fdb) {
    const int b = blockIdx.z, c0 = blockIdx.y * 64, n0 = blockIdx.x * 64;
    const int t = threadIdx.x;
    const int n4 = n0 + (t & 15) * 4;
    const int c4 = c0 + (t >> 4) * 4;
    const size_t base = (size_t)b * C_ * N_;
    float v[4][4];
    #pragma unroll
    for (int j = 0; j < 4; ++j) {
        const float4 m4 = *(const float4*)(fm + base + (size_t)(c4 + j) * N_ + n4);
        const float4 d4 = *(const float4*)(fd + base + (size_t)(c4 + j) * N_ + n4);
        v[j][0] = m4.x + d4.x; v[j][1] = m4.y + d4.y;
        v[j][2] = m4.z + d4.z; v[j][3] = m4.w + d4.w;
        ushort4 fo; fo.x = f2bf(d4.x); fo.y = f2bf(d4.y); fo.z = f2bf(d4.z); fo.w = f2bf(d4.w);
        *(ushort4*)(fdb + base + (size_t)(c4 + j) * N_ + n4) = fo;
    }
    #pragma unroll
    for (int i = 0; i < 4; ++i) {
        ushort4 xo;
        xo.x = f2bf(v[0][i]); xo.y = f2bf(v[1][i]);
        xo.z = f2bf(v[2][i]); xo.w = f2bf(v[3][i]);
        *(ushort4*)(xbT + ((size_t)b * N_ + (n4 + i)) * C_ + c4) = xo;
    }
}

// ---------------------------------------------------------------------------
// P1: dg[row] = sum_c bf16(x)^2.  4 threads per row + shfl merge.
// ---------------------------------------------------------------------------
__global__ __launch_bounds__(256) void diag_kernel(const ushort* __restrict__ xbT,
                                                   float* __restrict__ dg) {
    const int gid = blockIdx.x * 256 + threadIdx.x;   // 0..4*B*N-1
    const int row = gid >> 2, qtr = gid & 3;
    const ushort* p = xbT + (size_t)row * C_ + qtr * 64;
    float s = 0.f;
    #pragma unroll
    for (int c = 0; c < 64; c += 8) {
        const uint4 w4 = *(const uint4*)(p + c);
        float f;
        f = bflo(w4.x); s = fmaf(f, f, s); f = bfhi(w4.x); s = fmaf(f, f, s);
        f = bflo(w4.y); s = fmaf(f, f, s); f = bfhi(w4.y); s = fmaf(f, f, s);
        f = bflo(w4.z); s = fmaf(f, f, s); f = bfhi(w4.z); s = fmaf(f, f, s);
        f = bflo(w4.w); s = fmaf(f, f, s); f = bfhi(w4.w); s = fmaf(f, f, s);
    }
    s += __shfl_xor(s, 1, 64);
    s += __shfl_xor(s, 2, 64);
    if (qtr == 0) dg[row] = s;
}

// ---------------------------------------------------------------------------
// K2: lsum[n] += sum_m exp(S[n,m] - dg[n]).  Zero LDS.
// 256 thr (4 waves), grid (N/64, 2 m-halves, B).  Wave holds ALL 64 n-rows'
// A-frags in registers (32 short8); per 64-m chunk it owns a 16-m strip:
// 8 global B-frag loads -> 32 MFMAs.  Row-sum merge via shfl + atomicAdd.
// ---------------------------------------------------------------------------
__global__ __launch_bounds__(256, 2) void lsum_kernel(const ushort* __restrict__ xbT,
                                                      const float* __restrict__ dg,
                                                      float* __restrict__ lsum) {
    const int b = blockIdx.z, mh = blockIdx.y, n0 = blockIdx.x * 64;
    const int t = threadIdx.x, lane = t & 63, w = t >> 6;
    const int l15 = lane & 15, q = lane >> 4;
    const size_t xb = (size_t)b * N_ * C_;

    short8 af[4][8];
    #pragma unroll
    for (int ns = 0; ns < 4; ++ns)
        #pragma unroll
        for (int kk = 0; kk < 8; ++kk)
            af[ns][kk] = *(const short8*)(xbT + xb + (size_t)(n0 + 16 * ns + l15) * C_ + 32 * kk + 8 * q);
    float dv[4][4];
    #pragma unroll
    for (int ns = 0; ns < 4; ++ns)
        #pragma unroll
        for (int r = 0; r < 4; ++r)
            dv[ns][r] = dg[b * N_ + n0 + 16 * ns + 4 * q + r];

    float rs[4][4] = {};
    const int mbase = mh * 2048 + 16 * w;
    for (int mc = 0; mc < 2048; mc += 64) {
        short8 bf[8];
        #pragma unroll
        for (int kk = 0; kk < 8; ++kk)
            bf[kk] = *(const short8*)(xbT + xb + (size_t)(mbase + mc + l15) * C_ + 32 * kk + 8 * q);
        f32x4 a0 = {0.f,0.f,0.f,0.f}, a1 = {0.f,0.f,0.f,0.f};
        f32x4 a2 = {0.f,0.f,0.f,0.f}, a3 = {0.f,0.f,0.f,0.f};
        #pragma unroll
        for (int kk = 0; kk < 8; ++kk) {
            a0 = __builtin_amdgcn_mfma_f32_16x16x32_bf16(af[0][kk], bf[kk], a0, 0, 0, 0);
            a1 = __builtin_amdgcn_mfma_f32_16x16x32_bf16(af[1][kk], bf[kk], a1, 0, 0, 0);
            a2 = __builtin_amdgcn_mfma_f32_16x16x32_bf16(af[2][kk], bf[kk], a2, 0, 0, 0);
            a3 = __builtin_amdgcn_mfma_f32_16x16x32_bf16(af[3][kk], bf[kk], a3, 0, 0, 0);
        }
        #pragma unroll
        for (int r = 0; r < 4; ++r) {
            rs[0][r] += __expf(a0[r] - dv[0][r]);
            rs[1][r] += __expf(a1[r] - dv[1][r]);
            rs[2][r] += __expf(a2[r] - dv[2][r]);
            rs[3][r] += __expf(a3[r] - dv[3][r]);
        }
    }
    #pragma unroll
    for (int off = 1; off < 16; off <<= 1)
        #pragma unroll
        for (int ns = 0; ns < 4; ++ns)
            #pragma unroll
            for (int r = 0; r < 4; ++r)
                rs[ns][r] += __shfl_xor(rs[ns][r], off, 64);
    if (l15 == 0)
        #pragma unroll
        for (int ns = 0; ns < 4; ++ns)
            #pragma unroll
            for (int r = 0; r < 4; ++r)
                atomicAdd(lsum + b * N_ + n0 + 16 * ns + 4 * q + r, rs[ns][r]);
}

// ---------------------------------------------------------------------------
// P3: g = d + log(l)
// ---------------------------------------------------------------------------
__global__ __launch_bounds__(256) void g_kernel(const float* __restrict__ dg,
                                                float* __restrict__ lg) {
    const int gid = blockIdx.x * 256 + threadIdx.x;
    lg[gid] = dg[gid] + __logf(lg[gid]);
}

// ---------------------------------------------------------------------------
// K3: out[c,m] = sum_n fd[c,n]*exp(S[n,m]-g[n]) + fd[c,m]
// 256 thr (4 waves), m-tile 32, grid (N/32, B) = 512 blocks (2/CU).
// Xm B-frags persistent in registers; Xn and Fd A-frags straight from global.
// Only E goes through LDS (double-buffered, ONE barrier per 64-n chunk).
// ---------------------------------------------------------------------------
__global__ __launch_bounds__(256, 2) void out_kernel(const ushort* __restrict__ xbT,
                                                     const ushort* __restrict__ fdb,
                                                     const float* __restrict__ gg,
                                                     const float* __restrict__ fd32,
                                                     float* __restrict__ outp) {
    __shared__ ushort ET[2][32][LDE];   // [buf][m-local][n-local(64)]
    const int b = blockIdx.y, m0 = blockIdx.x * 32;
    const int t = threadIdx.x, lane = t & 63, w = t >> 6;
    const int l15 = lane & 15, q = lane >> 4;
    const size_t xb = (size_t)b * N_ * C_;   // xbT batch base
    const size_t fb = (size_t)b * C_ * N_;   // fdb / fd32 / out batch base

    // persistent B-frags of the m-panel (Xm), loaded once from global
    short8 bfr[2][8];
    #pragma unroll
    for (int mj = 0; mj < 2; ++mj)
        #pragma unroll
        for (int kk = 0; kk < 8; ++kk)
            bfr[mj][kk] = *(const short8*)(xbT + xb + (size_t)(m0 + 16 * mj + l15) * C_ + 32 * kk + 8 * q);

    f32x4 acc_o[4][2];
    #pragma unroll
    for (int cs = 0; cs < 4; ++cs)
        #pragma unroll
        for (int mj = 0; mj < 2; ++mj)
            acc_o[cs][mj] = (f32x4){0.f, 0.f, 0.f, 0.f};

    int p = 0;
    for (int n0 = 0; n0 < N_; n0 += 64, p ^= 1) {
        // ---- phase A: S[16w..+16][m0..+32] from global A-frags ----
        short8 af[8];
        #pragma unroll
        for (int kk = 0; kk < 8; ++kk)
            af[kk] = *(const short8*)(xbT + xb + (size_t)(n0 + 16 * w + l15) * C_ + 32 * kk + 8 * q);
        f32x4 s0 = {0.f,0.f,0.f,0.f}, s1 = {0.f,0.f,0.f,0.f};
        #pragma unroll
        for (int kk = 0; kk < 8; ++kk) {
            s0 = __builtin_amdgcn_mfma_f32_16x16x32_bf16(af[kk], bfr[0][kk], s0, 0, 0, 0);
            s1 = __builtin_amdgcn_mfma_f32_16x16x32_bf16(af[kk], bfr[1][kk], s1, 0, 0, 0);
        }
        // ---- E^T = bf16(exp(S - g[n])) into LDS (lane's rows n=16w+4q+r, col m) ----
        float gv[4];
        #pragma unroll
        for (int r = 0; r < 4; ++r) gv[r] = gg[b * N_ + n0 + 16 * w + 4 * q + r];
        {
            ushort4 e0, e1;
            e0.x = f2bf(__expf(s0[0] - gv[0])); e0.y = f2bf(__expf(s0[1] - gv[1]));
            e0.z = f2bf(__expf(s0[2] - gv[2])); e0.w = f2bf(__expf(s0[3] - gv[3]));
            e1.x = f2bf(__expf(s1[0] - gv[0])); e1.y = f2bf(__expf(s1[1] - gv[1]));
            e1.z = f2bf(__expf(s1[2] - gv[2])); e1.w = f2bf(__expf(s1[3] - gv[3]));
            *(ushort4*)(&ET[p][l15][16 * w + 4 * q])      = e0;
            *(ushort4*)(&ET[p][16 + l15][16 * w + 4 * q]) = e1;
        }
        __syncthreads();
        // ---- phase C: out[64w..+64][m0..+32] += Fd * E  (Fd A-frags from global) ----
        #pragma unroll
        for (int kk = 0; kk < 2; ++kk) {
            const short8 be0 = *(const short8*)(&ET[p][l15][32 * kk + 8 * q]);
            const short8 be1 = *(const short8*)(&ET[p][16 + l15][32 * kk + 8 * q]);
            #pragma unroll
            for (int cs = 0; cs < 4; ++cs) {
                const short8 afd = *(const short8*)(fdb + fb +
                    (size_t)(64 * w + 16 * cs + l15) * N_ + n0 + 32 * kk + 8 * q);
                acc_o[cs][0] = __builtin_amdgcn_mfma_f32_16x16x32_bf16(afd, be0, acc_o[cs][0], 0, 0, 0);
                acc_o[cs][1] = __builtin_amdgcn_mfma_f32_16x16x32_bf16(afd, be1, acc_o[cs][1], 0, 0, 0);
            }
        }
        // no second barrier: double-buffered ET + the one barrier above make it safe
    }
    // ---- epilogue: + fp32 residual ----
    #pragma unroll
    for (int cs = 0; cs < 4; ++cs)
        #pragma unroll
        for (int mj = 0; mj < 2; ++mj)
            #pragma unroll
            for (int r = 0; r < 4; ++r) {
                const int c = 64 * w + 16 * cs + 4 * q + r;
                const int m = m0 + 16 * mj + l15;
                const size_t o = fb + (size_t)c * N_ + m;
                outp[o] = acc_o[cs][mj][r] + fd32[o];
            }
}

// ---------------------------------------------------------------------------
extern "C" void kernel_launch(void* const* d_in, const int* in_sizes, int n_in,
                              void* d_out, int out_size, void* d_ws, size_t ws_size,
                              hipStream_t stream) {
    const float* fm = (const float*)d_in[0];
    const float* fd = (const float*)d_in[1];
    float* outp = (float*)d_out;

    const size_t xb_elts = (size_t)B_ * N_ * C_;
    const size_t need = xb_elts * 2 * 2 + (size_t)B_ * N_ * 4 * 2;  // ~16.9 MB
    if (ws_size < need) return;

    ushort* xbT = (ushort*)d_ws;
    ushort* fdb = xbT + xb_elts;
    float*  dg  = (float*)(fdb + xb_elts);
    float*  lg  = dg + (size_t)B_ * N_;

    prep_kernel<<<dim3(N_ / 64, C_ / 64, B_), 256, 0, stream>>>(fm, fd, xbT, fdb);
    diag_kernel<<<dim3(B_ * N_ * 4 / 256), 256, 0, stream>>>(xbT, dg);
    hipMemsetAsync(lg, 0, (size_t)B_ * N_ * sizeof(float), stream);
    lsum_kernel<<<dim3(N_ / 64, 2, B_), 256, 0, stream>>>(xbT, dg, lg);
    g_kernel<<<dim3(B_ * N_ / 256), 256, 0, stream>>>(dg, lg);
    out_kernel<<<dim3(N_ / 32, B_), 256, 0, stream>>>(xbT, fdb, lg, fd, outp);
}

// Round 4
// 383.929 us; speedup vs baseline: 1.0845x; 1.0845x over previous
//
#include <hip/hip_runtime.h>
#include <math.h>

#define B_ 4
#define C_ 256
#define N_ 4096   // H*W
#define LDE 68    // ET row stride (ushorts)

typedef __attribute__((ext_vector_type(8))) short short8;
typedef __attribute__((ext_vector_type(4))) float f32x4;

__device__ inline ushort f2bf(float f) {
    uint u = __float_as_uint(f);
    return (ushort)((u + 0x7fffu + ((u >> 16) & 1u)) >> 16);   // RNE
}
__device__ inline float bf2f(ushort h) { return __uint_as_float(((uint)h) << 16); }

__device__ inline f32x4 mfma16(short8 a, short8 b, f32x4 c) {
    return __builtin_amdgcn_mfma_f32_16x16x32_bf16(a, b, c, 0, 0, 0);
}

// ---------------------------------------------------------------------------
// P0: xbT[b][n][c] = bf16(fm+fd) (transposed), fdb[b][c][n] = bf16(fd),
//     dg[b*N+n] += sum_c bf16(x)^2  (fused diag, atomicAdd partials).
// 64x64 tile, LDS transpose: BOTH global sides coalesced.
// ---------------------------------------------------------------------------
__global__ __launch_bounds__(256) void prep_kernel(const float* __restrict__ fm,
                                                   const float* __restrict__ fd,
                                                   ushort* __restrict__ xbT,
                                                   ushort* __restrict__ fdb,
                                                   float* __restrict__ dg) {
    __shared__ ushort xl[64][68];   // [c-local][n-local], pad 68 (8B-aligned rows)
    const int b = blockIdx.z, c0 = blockIdx.y * 64, n0 = blockIdx.x * 64;
    const int t = threadIdx.x;
    const int n4 = (t & 15) * 4, cl = t >> 4;
    const size_t base = (size_t)b * C_ * N_;
    float dsum[4] = {0.f, 0.f, 0.f, 0.f};
    #pragma unroll
    for (int p = 0; p < 4; ++p) {
        const int cr = 16 * p + cl;
        const float4 m4 = *(const float4*)(fm + base + (size_t)(c0 + cr) * N_ + n0 + n4);
        const float4 d4 = *(const float4*)(fd + base + (size_t)(c0 + cr) * N_ + n0 + n4);
        ushort4 fo;
        fo.x = f2bf(d4.x); fo.y = f2bf(d4.y); fo.z = f2bf(d4.z); fo.w = f2bf(d4.w);
        *(ushort4*)(fdb + base + (size_t)(c0 + cr) * N_ + n0 + n4) = fo;
        ushort4 xo;
        xo.x = f2bf(m4.x + d4.x); xo.y = f2bf(m4.y + d4.y);
        xo.z = f2bf(m4.z + d4.z); xo.w = f2bf(m4.w + d4.w);
        *(ushort4*)(&xl[cr][n4]) = xo;
        // diag uses the bf16-rounded value (matches the MFMA Gram diagonal closely)
        float r0 = bf2f(xo.x), r1 = bf2f(xo.y), r2 = bf2f(xo.z), r3 = bf2f(xo.w);
        dsum[0] = fmaf(r0, r0, dsum[0]); dsum[1] = fmaf(r1, r1, dsum[1]);
        dsum[2] = fmaf(r2, r2, dsum[2]); dsum[3] = fmaf(r3, r3, dsum[3]);
    }
    // reduce over the 16 c-rows this wave covered (t>>4 varies by xor 16/32 in t)
    #pragma unroll
    for (int j = 0; j < 4; ++j) {
        dsum[j] += __shfl_xor(dsum[j], 16, 64);
        dsum[j] += __shfl_xor(dsum[j], 32, 64);
    }
    if (((t >> 4) & 3) == 0) {
        #pragma unroll
        for (int j = 0; j < 4; ++j)
            atomicAdd(dg + b * N_ + n0 + n4 + j, dsum[j]);
    }
    __syncthreads();
    // phase 2: write xbT rows n, coalesced in c
    #pragma unroll
    for (int p = 0; p < 4; ++p) {
        const int nr = 16 * p + cl;
        const int c4 = (t & 15) * 4;
        ushort4 g;
        g.x = xl[c4 + 0][nr]; g.y = xl[c4 + 1][nr];
        g.z = xl[c4 + 2][nr]; g.w = xl[c4 + 3][nr];
        *(ushort4*)(xbT + ((size_t)b * N_ + n0 + nr) * C_ + c0 + c4) = g;
    }
}

// ---------------------------------------------------------------------------
// K2: lg[n] = dg[n] + log( sum_m exp(S[n,m]-dg[n]) ).  Zero staging LDS.
// 512 thr, grid 256 (XCD-swizzled). Wave: n-pair (w&1) A-frags persistent in
// registers; m-tile (w>>1) B-frags prefetched 1 chunk ahead. No loop barriers.
// ---------------------------------------------------------------------------
__global__ __launch_bounds__(512, 2) void lsum_kernel(const ushort* __restrict__ xbT,
                                                      const float* __restrict__ dg,
                                                      float* __restrict__ lg) {
    __shared__ float red[8][32];
    const int bid = blockIdx.x;
    const int b = (bid >> 1) & 3;
    const int n0 = ((((bid >> 3) << 1) | (bid & 1))) * 64;
    const int t = threadIdx.x, lane = t & 63, w = t >> 6;
    const int l15 = lane & 15, q = lane >> 4;
    const int p2 = w & 1, mt = w >> 1;
    const size_t xb = (size_t)b * N_ * C_;

    short8 af[2][8];
    #pragma unroll
    for (int i = 0; i < 2; ++i)
        #pragma unroll
        for (int kk = 0; kk < 8; ++kk)
            af[i][kk] = *(const short8*)(xbT + xb +
                (size_t)(n0 + 32 * p2 + 16 * i + l15) * C_ + 32 * kk + 8 * q);
    float dv[2][4];
    #pragma unroll
    for (int i = 0; i < 2; ++i)
        #pragma unroll
        for (int r = 0; r < 4; ++r)
            dv[i][r] = dg[b * N_ + n0 + 32 * p2 + 16 * i + 4 * q + r];

    short8 bn[8];
    #pragma unroll
    for (int kk = 0; kk < 8; ++kk)
        bn[kk] = *(const short8*)(xbT + xb + (size_t)(16 * mt + l15) * C_ + 32 * kk + 8 * q);

    float rs[2][4] = {};
    for (int mc = 0; mc < 64; ++mc) {
        short8 bc[8];
        #pragma unroll
        for (int kk = 0; kk < 8; ++kk) bc[kk] = bn[kk];
        const int nx = (mc + 1 < 64) ? (mc + 1) * 64 : 0;   // harmless wrap
        #pragma unroll
        for (int kk = 0; kk < 8; ++kk)
            bn[kk] = *(const short8*)(xbT + xb +
                (size_t)(nx + 16 * mt + l15) * C_ + 32 * kk + 8 * q);
        f32x4 a0 = {0.f,0.f,0.f,0.f}, a1 = {0.f,0.f,0.f,0.f};
        #pragma unroll
        for (int kk = 0; kk < 8; ++kk) {
            a0 = mfma16(af[0][kk], bc[kk], a0);
            a1 = mfma16(af[1][kk], bc[kk], a1);
        }
        #pragma unroll
        for (int r = 0; r < 4; ++r) {
            rs[0][r] += __expf(a0[r] - dv[0][r]);
            rs[1][r] += __expf(a1[r] - dv[1][r]);
        }
    }
    #pragma unroll
    for (int off = 1; off < 16; off <<= 1)
        #pragma unroll
        for (int i = 0; i < 2; ++i)
            #pragma unroll
            for (int r = 0; r < 4; ++r)
                rs[i][r] += __shfl_xor(rs[i][r], off, 64);
    if (l15 == 0) {
        #pragma unroll
        for (int i = 0; i < 2; ++i)
            #pragma unroll
            for (int r = 0; r < 4; ++r)
                red[w][16 * i + 4 * q + r] = rs[i][r];
    }
    __syncthreads();
    if (t < 64) {
        const int pp = t >> 5, nn = t & 31;
        const float s = red[pp][nn] + red[pp + 2][nn] + red[pp + 4][nn] + red[pp + 6][nn];
        const int gi = b * N_ + n0 + 32 * pp + nn;
        lg[gi] = dg[gi] + __logf(s);
    }
}

// ---------------------------------------------------------------------------
// K3: out[c,m] = sum_n fd[c,n]*exp(S[n,m]-g[n]) + fd[c,m]
// 512 thr, grid 256 (XCD-swizzled), m-tile 64. Xm B-frags persistent; Xn/Fd
// A-frags + g register-prefetched 1 chunk ahead; ET dbuf in LDS; ONE
// lgkm-only barrier per chunk (prefetch loads stay in flight across it).
// ---------------------------------------------------------------------------
__global__ __launch_bounds__(512, 2) void out_kernel(const ushort* __restrict__ xbT,
                                                     const ushort* __restrict__ fdb,
                                                     const float* __restrict__ gg,
                                                     const float* __restrict__ fd32,
                                                     float* __restrict__ outp) {
    __shared__ ushort ET[2][64][LDE];   // [buf][m-local][n-local]
    const int bid = blockIdx.x;
    const int b = (bid >> 1) & 3;
    const int m0 = ((((bid >> 3) << 1) | (bid & 1))) * 64;
    const int t = threadIdx.x, lane = t & 63, w = t >> 6;
    const int l15 = lane & 15, q = lane >> 4;
    const int a = w & 3, h = w >> 2;     // phase A: n-tile a, m-pair h
    const size_t xb = (size_t)b * N_ * C_;
    const size_t fb = (size_t)b * C_ * N_;

    short8 bfr[2][8];                    // persistent Xm B-frags (m-tiles 2h, 2h+1)
    #pragma unroll
    for (int jt = 0; jt < 2; ++jt)
        #pragma unroll
        for (int kk = 0; kk < 8; ++kk)
            bfr[jt][kk] = *(const short8*)(xbT + xb +
                (size_t)(m0 + 32 * h + 16 * jt + l15) * C_ + 32 * kk + 8 * q);

    f32x4 acc[2][4];
    #pragma unroll
    for (int ct = 0; ct < 2; ++ct)
        #pragma unroll
        for (int mt = 0; mt < 4; ++mt)
            acc[ct][mt] = (f32x4){0.f, 0.f, 0.f, 0.f};

    // prefetch chunk 0
    short8 an[8];
    #pragma unroll
    for (int kk = 0; kk < 8; ++kk)
        an[kk] = *(const short8*)(xbT + xb + (size_t)(16 * a + l15) * C_ + 32 * kk + 8 * q);
    short8 fn[2][2];
    #pragma unroll
    for (int ct = 0; ct < 2; ++ct)
        #pragma unroll
        for (int k2 = 0; k2 < 2; ++k2)
            fn[ct][k2] = *(const short8*)(fdb + fb +
                (size_t)(32 * w + 16 * ct + l15) * N_ + 32 * k2 + 8 * q);
    float gn[4];
    #pragma unroll
    for (int r = 0; r < 4; ++r) gn[r] = gg[b * N_ + 16 * a + 4 * q + r];

    int p = 0;
    for (int n0c = 0; n0c < N_; n0c += 64, p ^= 1) {
        short8 ac[8];
        #pragma unroll
        for (int kk = 0; kk < 8; ++kk) ac[kk] = an[kk];
        short8 fc[2][2];
        #pragma unroll
        for (int ct = 0; ct < 2; ++ct)
            #pragma unroll
            for (int k2 = 0; k2 < 2; ++k2) fc[ct][k2] = fn[ct][k2];
        float gv[4];
        #pragma unroll
        for (int r = 0; r < 4; ++r) gv[r] = gn[r];

        const int nx = (n0c + 64 < N_) ? n0c + 64 : 0;   // harmless wrap
        #pragma unroll
        for (int kk = 0; kk < 8; ++kk)
            an[kk] = *(const short8*)(xbT + xb +
                (size_t)(nx + 16 * a + l15) * C_ + 32 * kk + 8 * q);
        #pragma unroll
        for (int ct = 0; ct < 2; ++ct)
            #pragma unroll
            for (int k2 = 0; k2 < 2; ++k2)
                fn[ct][k2] = *(const short8*)(fdb + fb +
                    (size_t)(32 * w + 16 * ct + l15) * N_ + nx + 32 * k2 + 8 * q);
        #pragma unroll
        for (int r = 0; r < 4; ++r) gn[r] = gg[b * N_ + nx + 16 * a + 4 * q + r];

        // ---- phase A: S tiles (a, 2h), (a, 2h+1) ----
        f32x4 s0 = {0.f,0.f,0.f,0.f}, s1 = {0.f,0.f,0.f,0.f};
        #pragma unroll
        for (int kk = 0; kk < 8; ++kk) {
            s0 = mfma16(ac[kk], bfr[0][kk], s0);
            s1 = mfma16(ac[kk], bfr[1][kk], s1);
        }
        // ---- phase B: E^T = bf16(exp(S-g)) -> ET[p][m][n] ----
        ushort4 e0, e1;
        e0.x = f2bf(__expf(s0[0] - gv[0])); e0.y = f2bf(__expf(s0[1] - gv[1]));
        e0.z = f2bf(__expf(s0[2] - gv[2])); e0.w = f2bf(__expf(s0[3] - gv[3]));
        e1.x = f2bf(__expf(s1[0] - gv[0])); e1.y = f2bf(__expf(s1[1] - gv[1]));
        e1.z = f2bf(__expf(s1[2] - gv[2])); e1.w = f2bf(__expf(s1[3] - gv[3]));
        *(ushort4*)(&ET[p][32 * h + l15][16 * a + 4 * q])      = e0;
        *(ushort4*)(&ET[p][32 * h + 16 + l15][16 * a + 4 * q]) = e1;

        // lgkm-only barrier: ds ops drained, prefetch vmem stays in flight
        asm volatile("s_waitcnt lgkmcnt(0)\n\ts_barrier" ::: "memory");

        // ---- phase C: out[32w..+32][m0..+64] += Fd * E ----
        #pragma unroll
        for (int k2 = 0; k2 < 2; ++k2) {
            #pragma unroll
            for (int mt = 0; mt < 4; ++mt) {
                const short8 be = *(const short8*)(&ET[p][16 * mt + l15][32 * k2 + 8 * q]);
                acc[0][mt] = mfma16(fc[0][k2], be, acc[0][mt]);
                acc[1][mt] = mfma16(fc[1][k2], be, acc[1][mt]);
            }
        }
    }
    // ---- epilogue: + fp32 residual ----
    #pragma unroll
    for (int ct = 0; ct < 2; ++ct)
        #pragma unroll
        for (int mt = 0; mt < 4; ++mt)
            #pragma unroll
            for (int r = 0; r < 4; ++r) {
                const int c = 32 * w + 16 * ct + 4 * q + r;
                const int m = m0 + 16 * mt + l15;
                const size_t o = fb + (size_t)c * N_ + m;
                outp[o] = acc[ct][mt][r] + fd32[o];
            }
}

// ---------------------------------------------------------------------------
extern "C" void kernel_launch(void* const* d_in, const int* in_sizes, int n_in,
                              void* d_out, int out_size, void* d_ws, size_t ws_size,
                              hipStream_t stream) {
    const float* fm = (const float*)d_in[0];
    const float* fd = (const float*)d_in[1];
    float* outp = (float*)d_out;

    const size_t xb_elts = (size_t)B_ * N_ * C_;
    const size_t need = xb_elts * 2 * 2 + (size_t)B_ * N_ * 4 * 2;  // ~17 MB
    if (ws_size < need) return;

    ushort* xbT = (ushort*)d_ws;
    ushort* fdb = xbT + xb_elts;
    float*  dg  = (float*)(fdb + xb_elts);
    float*  lg  = dg + (size_t)B_ * N_;

    hipMemsetAsync(dg, 0, (size_t)B_ * N_ * sizeof(float), stream);
    prep_kernel<<<dim3(N_ / 64, C_ / 64, B_), 256, 0, stream>>>(fm, fd, xbT, fdb, dg);
    lsum_kernel<<<dim3(256), 512, 0, stream>>>(xbT, dg, lg);
    out_kernel<<<dim3(256), 512, 0, stream>>>(xbT, fdb, lg, fd, outp);
}

// Round 5
// 195.382 us; speedup vs baseline: 2.1310x; 1.9650x over previous
//
#include <hip/hip_runtime.h>
#include <math.h>

#define B_ 4
#define C_ 256
#define N_ 4096   // H*W
#define LDE 68    // ET row stride (ushorts) — round-4 verified, 0 conflicts
#define LDX 72    // prep LDS tile stride (ushorts), 144 B = 16-B multiple

typedef __attribute__((ext_vector_type(8))) short short8;
typedef __attribute__((ext_vector_type(4))) float f32x4;

__device__ inline ushort f2bf(float f) {
    uint u = __float_as_uint(f);
    return (ushort)((u + 0x7fffu + ((u >> 16) & 1u)) >> 16);   // RNE
}
__device__ inline float bf2f(ushort h) { return __uint_as_float(((uint)h) << 16); }

__device__ inline f32x4 mfma16(short8 a, short8 b, f32x4 c) {
    return __builtin_amdgcn_mfma_f32_16x16x32_bf16(a, b, c, 0, 0, 0);
}

// Fragment-order layouts (lane l <-> (row l&15, k-group l>>4); 16 B per lane):
//   xfrag[b][nt=0..255][kk=0..7][lane=0..63][8 ushorts]   (X = bf16(fm+fd), k=c)
//   ffrag[b][nc=0..63][ct=0..15][k2=0..1][lane=0..63][8]  (Fd bf16, k=n within chunk)
__device__ inline size_t xfi(int b, int nt, int kk) {
    return (((size_t)(b * 256 + nt)) * 8 + kk) * 512;
}
__device__ inline size_t ffi(int b, int nc, int ct, int k2) {
    return ((((size_t)(b * 64 + nc)) * 16 + ct) * 2 + k2) * 512;
}

// ---------------------------------------------------------------------------
// P0: build xfrag + ffrag (MFMA-native order) + dg (diag, fused, atomicAdd).
// 64x64 tile; LDS holds bf16 X and bf16 Fd tiles for the lane-order shuffle.
// ---------------------------------------------------------------------------
__global__ __launch_bounds__(256) void prep_kernel(const float* __restrict__ fm,
                                                   const float* __restrict__ fd,
                                                   ushort* __restrict__ xfrag,
                                                   ushort* __restrict__ ffrag,
                                                   float* __restrict__ dg) {
    __shared__ ushort xl[64][LDX];   // [c-local][n-local]
    __shared__ ushort fl[64][LDX];   // [c-local][n-local]
    const int b = blockIdx.z, c0 = blockIdx.y * 64, n0 = blockIdx.x * 64;
    const int t = threadIdx.x;
    const int n4 = (t & 15) * 4, cl = t >> 4;
    const size_t base = (size_t)b * C_ * N_;
    float dsum[4] = {0.f, 0.f, 0.f, 0.f};
    #pragma unroll
    for (int p = 0; p < 4; ++p) {
        const int cr = 16 * p + cl;
        const float4 m4 = *(const float4*)(fm + base + (size_t)(c0 + cr) * N_ + n0 + n4);
        const float4 d4 = *(const float4*)(fd + base + (size_t)(c0 + cr) * N_ + n0 + n4);
        ushort4 fo;
        fo.x = f2bf(d4.x); fo.y = f2bf(d4.y); fo.z = f2bf(d4.z); fo.w = f2bf(d4.w);
        *(ushort4*)(&fl[cr][n4]) = fo;
        ushort4 xo;
        xo.x = f2bf(m4.x + d4.x); xo.y = f2bf(m4.y + d4.y);
        xo.z = f2bf(m4.z + d4.z); xo.w = f2bf(m4.w + d4.w);
        *(ushort4*)(&xl[cr][n4]) = xo;
        float r0 = bf2f(xo.x), r1 = bf2f(xo.y), r2 = bf2f(xo.z), r3 = bf2f(xo.w);
        dsum[0] = fmaf(r0, r0, dsum[0]); dsum[1] = fmaf(r1, r1, dsum[1]);
        dsum[2] = fmaf(r2, r2, dsum[2]); dsum[3] = fmaf(r3, r3, dsum[3]);
    }
    #pragma unroll
    for (int j = 0; j < 4; ++j) {
        dsum[j] += __shfl_xor(dsum[j], 16, 64);
        dsum[j] += __shfl_xor(dsum[j], 32, 64);
    }
    if (((t >> 4) & 3) == 0) {
        #pragma unroll
        for (int j = 0; j < 4; ++j)
            atomicAdd(dg + b * N_ + n0 + n4 + j, dsum[j]);
    }
    __syncthreads();
    const int l = t & 63, tl = t >> 6;     // tl = local tile index 0..3
    // ---- xfrag: lane l <- row 16*tl+(l&15), c ushorts 32*kk+8*(l>>4) ----
    {
        const int nl = 16 * tl + (l & 15);
        #pragma unroll
        for (int j = 0; j < 2; ++j) {
            const int kk = (c0 >> 5) + j;
            const int cb = 32 * j + 8 * (l >> 4);   // c-local ushort offset
            ushort v[8];
            #pragma unroll
            for (int i = 0; i < 8; ++i) v[i] = xl[cb + i][nl];
            ushort* dst = xfrag + xfi(b, (n0 >> 4) + tl, kk) + l * 8;
            ushort4 v0 = {v[0], v[1], v[2], v[3]}, v1 = {v[4], v[5], v[6], v[7]};
            *(ushort4*)(dst) = v0; *(ushort4*)(dst + 4) = v1;
        }
    }
    // ---- ffrag: lane l <- c-row 16*tl+(l&15), n ushorts 32*k2+8*(l>>4) ----
    {
        const int row = 16 * tl + (l & 15);
        #pragma unroll
        for (int k2 = 0; k2 < 2; ++k2) {
            const int col = 32 * k2 + 8 * (l >> 4);
            const ushort4 a0 = *(const ushort4*)(&fl[row][col]);
            const ushort4 a1 = *(const ushort4*)(&fl[row][col + 4]);
            ushort* dst = ffrag + ffi(b, n0 >> 6, (c0 >> 4) + tl, k2) + l * 8;
            *(ushort4*)(dst) = a0; *(ushort4*)(dst + 4) = a1;
        }
    }
}

// ---------------------------------------------------------------------------
// K2: lg[n] = dg[n] + log( sum_m exp(S[n,m]-dg[n]) ).  Zero staging LDS.
// 512 thr, grid 256 (XCD-swizzled). A-frags (64 n-rows) persistent in regs;
// B-frags single-buffer rotation (reload right after last use). All loads
// are coalesced 1-KB streams from xfrag.
// ---------------------------------------------------------------------------
__global__ __launch_bounds__(512, 2) void lsum_kernel(const ushort* __restrict__ xfrag,
                                                      const float* __restrict__ dg,
                                                      float* __restrict__ lg) {
    __shared__ float red[8][32];
    const int bid = blockIdx.x;
    const int b = (bid >> 1) & 3;
    const int n0 = ((((bid >> 3) << 1) | (bid & 1))) * 64;
    const int t = threadIdx.x, lane = t & 63, w = t >> 6;
    const int l15 = lane & 15, q = lane >> 4;
    const int p2 = w & 1, mt = w >> 1;

    short8 af[2][8];
    #pragma unroll
    for (int i = 0; i < 2; ++i)
        #pragma unroll
        for (int kk = 0; kk < 8; ++kk)
            af[i][kk] = *(const short8*)(xfrag + xfi(b, (n0 >> 4) + 2 * p2 + i, kk) + lane * 8);
    float dv[2][4];
    #pragma unroll
    for (int i = 0; i < 2; ++i)
        #pragma unroll
        for (int r = 0; r < 4; ++r)
            dv[i][r] = dg[b * N_ + n0 + 32 * p2 + 16 * i + 4 * q + r];

    short8 bn[8];
    #pragma unroll
    for (int kk = 0; kk < 8; ++kk)
        bn[kk] = *(const short8*)(xfrag + xfi(b, mt, kk) + lane * 8);

    float rs[2][4] = {};
    for (int mc = 0; mc < 64; ++mc) {
        const int MTn = ((mc + 1 < 64) ? mc + 1 : 0) * 4 + mt;   // harmless wrap
        f32x4 a0 = {0.f,0.f,0.f,0.f}, a1 = {0.f,0.f,0.f,0.f};
        #pragma unroll
        for (int kk = 0; kk < 8; ++kk) {
            a0 = mfma16(af[0][kk], bn[kk], a0);
            a1 = mfma16(af[1][kk], bn[kk], a1);
            bn[kk] = *(const short8*)(xfrag + xfi(b, MTn, kk) + lane * 8);
        }
        #pragma unroll
        for (int r = 0; r < 4; ++r) {
            rs[0][r] += __expf(a0[r] - dv[0][r]);
            rs[1][r] += __expf(a1[r] - dv[1][r]);
        }
    }
    #pragma unroll
    for (int off = 1; off < 16; off <<= 1)
        #pragma unroll
        for (int i = 0; i < 2; ++i)
            #pragma unroll
            for (int r = 0; r < 4; ++r)
                rs[i][r] += __shfl_xor(rs[i][r], off, 64);
    if (l15 == 0) {
        #pragma unroll
        for (int i = 0; i < 2; ++i)
            #pragma unroll
            for (int r = 0; r < 4; ++r)
                red[w][16 * i + 4 * q + r] = rs[i][r];
    }
    __syncthreads();
    if (t < 64) {
        const int pp = t >> 5, nn = t & 31;
        const float s = red[pp][nn] + red[pp + 2][nn] + red[pp + 4][nn] + red[pp + 6][nn];
        const int gi = b * N_ + n0 + 32 * pp + nn;
        lg[gi] = dg[gi] + __logf(s);
    }
}

// ---------------------------------------------------------------------------
// K3: out[c,m] = sum_n fd[c,n]*exp(S[n,m]-g[n]) + fd[c,m]
// 512 thr, grid 256 (XCD-swizzled), m-tile 64. Xm B-frags persistent; Xn
// A-frags single-buffer rotation (coalesced xfrag streams); Fd A-frags loaded
// top-of-chunk from ffrag; ET dbuf LDS with ONE lgkm-only barrier per chunk.
// ---------------------------------------------------------------------------
__global__ __launch_bounds__(512, 2) void out_kernel(const ushort* __restrict__ xfrag,
                                                     const ushort* __restrict__ ffrag,
                                                     const float* __restrict__ gg,
                                                     const float* __restrict__ fd32,
                                                     float* __restrict__ outp) {
    __shared__ ushort ET[2][64][LDE];   // [buf][m-local][n-local]
    const int bid = blockIdx.x;
    const int b = (bid >> 1) & 3;
    const int m0 = ((((bid >> 3) << 1) | (bid & 1))) * 64;
    const int t = threadIdx.x, lane = t & 63, w = t >> 6;
    const int l15 = lane & 15, q = lane >> 4;
    const int a = w & 3, h = w >> 2;     // phase A: n-tile a, m-pair h
    const size_t fb = (size_t)b * C_ * N_;

    short8 bfr[2][8];                    // persistent Xm B-frags
    #pragma unroll
    for (int jt = 0; jt < 2; ++jt)
        #pragma unroll
        for (int kk = 0; kk < 8; ++kk)
            bfr[jt][kk] = *(const short8*)(xfrag + xfi(b, (m0 >> 4) + 2 * h + jt, kk) + lane * 8);

    f32x4 acc[2][4];
    #pragma unroll
    for (int ct = 0; ct < 2; ++ct)
        #pragma unroll
        for (int mt = 0; mt < 4; ++mt)
            acc[ct][mt] = (f32x4){0.f, 0.f, 0.f, 0.f};

    short8 an[8];                        // A-frags, chunk 0
    #pragma unroll
    for (int kk = 0; kk < 8; ++kk)
        an[kk] = *(const short8*)(xfrag + xfi(b, a, kk) + lane * 8);
    float gn[4];
    #pragma unroll
    for (int r = 0; r < 4; ++r) gn[r] = gg[b * N_ + 16 * a + 4 * q + r];

    int p = 0;
    for (int n0c = 0; n0c < N_; n0c += 64, p ^= 1) {
        const int nc = n0c >> 6;
        // Fd A-frags for THIS chunk (used in phase C, ~600 cyc away)
        short8 fn[2][2];
        #pragma unroll
        for (int ct = 0; ct < 2; ++ct)
            #pragma unroll
            for (int k2 = 0; k2 < 2; ++k2)
                fn[ct][k2] = *(const short8*)(ffrag + ffi(b, nc, 2 * w + ct, k2) + lane * 8);
        float gv[4];
        #pragma unroll
        for (int r = 0; r < 4; ++r) gv[r] = gn[r];
        const int nx = (n0c + 64 < N_) ? n0c + 64 : 0;   // harmless wrap
        #pragma unroll
        for (int r = 0; r < 4; ++r) gn[r] = gg[b * N_ + nx + 16 * a + 4 * q + r];

        // ---- phase A: S tiles (a, 2h), (a, 2h+1); rotate an[] to next chunk ----
        f32x4 s0 = {0.f,0.f,0.f,0.f}, s1 = {0.f,0.f,0.f,0.f};
        #pragma unroll
        for (int kk = 0; kk < 8; ++kk) {
            s0 = mfma16(an[kk], bfr[0][kk], s0);
            s1 = mfma16(an[kk], bfr[1][kk], s1);
            an[kk] = *(const short8*)(xfrag + xfi(b, (nx >> 4) + a, kk) + lane * 8);
        }
        // ---- phase B: E^T = bf16(exp(S-g)) -> ET[p][m][n] ----
        ushort4 e0, e1;
        e0.x = f2bf(__expf(s0[0] - gv[0])); e0.y = f2bf(__expf(s0[1] - gv[1]));
        e0.z = f2bf(__expf(s0[2] - gv[2])); e0.w = f2bf(__expf(s0[3] - gv[3]));
        e1.x = f2bf(__expf(s1[0] - gv[0])); e1.y = f2bf(__expf(s1[1] - gv[1]));
        e1.z = f2bf(__expf(s1[2] - gv[2])); e1.w = f2bf(__expf(s1[3] - gv[3]));
        *(ushort4*)(&ET[p][32 * h + l15][16 * a + 4 * q])      = e0;
        *(ushort4*)(&ET[p][32 * h + 16 + l15][16 * a + 4 * q]) = e1;

        // lgkm-only barrier: ds ops drained, prefetch vmem stays in flight
        asm volatile("s_waitcnt lgkmcnt(0)\n\ts_barrier" ::: "memory");

        // ---- phase C: out[32w..+32][m0..+64] += Fd * E ----
        #pragma unroll
        for (int k2 = 0; k2 < 2; ++k2) {
            #pragma unroll
            for (int mt = 0; mt < 4; ++mt) {
                const short8 be = *(const short8*)(&ET[p][16 * mt + l15][32 * k2 + 8 * q]);
                acc[0][mt] = mfma16(fn[0][k2], be, acc[0][mt]);
                acc[1][mt] = mfma16(fn[1][k2], be, acc[1][mt]);
            }
        }
    }
    // ---- epilogue: + fp32 residual ----
    #pragma unroll
    for (int ct = 0; ct < 2; ++ct)
        #pragma unroll
        for (int mt = 0; mt < 4; ++mt)
            #pragma unroll
            for (int r = 0; r < 4; ++r) {
                const int c = 32 * w + 16 * ct + 4 * q + r;
                const int m = m0 + 16 * mt + l15;
                const size_t o = fb + (size_t)c * N_ + m;
                outp[o] = acc[ct][mt][r] + fd32[o];
            }
}

// ---------------------------------------------------------------------------
extern "C" void kernel_launch(void* const* d_in, const int* in_sizes, int n_in,
                              void* d_out, int out_size, void* d_ws, size_t ws_size,
                              hipStream_t stream) {
    const float* fm = (const float*)d_in[0];
    const float* fd = (const float*)d_in[1];
    float* outp = (float*)d_out;

    const size_t xb_elts = (size_t)B_ * N_ * C_;   // elements per frag array
    const size_t need = xb_elts * 2 * 2 + (size_t)B_ * N_ * 4 * 2;  // ~17 MB
    if (ws_size < need) return;

    ushort* xfrag = (ushort*)d_ws;
    ushort* ffrag = xfrag + xb_elts;
    float*  dg    = (float*)(ffrag + xb_elts);
    float*  lg    = dg + (size_t)B_ * N_;

    hipMemsetAsync(dg, 0, (size_t)B_ * N_ * sizeof(float), stream);
    prep_kernel<<<dim3(N_ / 64, C_ / 64, B_), 256, 0, stream>>>(fm, fd, xfrag, ffrag, dg);
    lsum_kernel<<<dim3(256), 512, 0, stream>>>(xfrag, dg, lg);
    out_kernel<<<dim3(256), 512, 0, stream>>>(xfrag, ffrag, lg, fd, outp);
}